// Round 1
// baseline (555.779 us; speedup 1.0000x reference)
//
#include <hip/hip_runtime.h>
#include <hip/hip_bf16.h>
#include <stdint.h>

// BitLinear: out[t,o] = (sum_i clip(rint(x[t,i]/xs),-128,127) * clip(rint(w[o,i]/ws),-1,1)) * xs*ws
// M=8192 tokens, N=4096 out_f, K=4096 in_f.
// Strategy: quantize both operands to bf16 (integers <=128 are exact in bf16),
// then m97-structure bf16 MFMA GEMM (A[M,K] x B[N,K]^T), fp32 accumulate (exact).

typedef __bf16 bf16x8 __attribute__((ext_vector_type(8)));
typedef float f32x4 __attribute__((ext_vector_type(4)));

typedef __attribute__((address_space(1))) void gvoid;
typedef __attribute__((address_space(3))) void lvoid;

#define M_DIM 8192
#define N_DIM 4096
#define K_DIM 4096

#define BM 128
#define BN 128
#define BK 32

// ---------------- quantize: fp32 -> bf16 integer values ----------------
// each thread: 8 elements (two float4 loads, one 16B store)
__global__ __launch_bounds__(256) void quant_kernel(
    const float* __restrict__ in, __hip_bfloat16* __restrict__ out,
    const float* __restrict__ scale_ptr, float lo, float hi, long n) {
  long i = ((long)blockIdx.x * blockDim.x + threadIdx.x) * 8;
  if (i >= n) return;
  float s = scale_ptr[0];
  float4 a = *(const float4*)(in + i);
  float4 b = *(const float4*)(in + i + 4);
  float v[8] = {a.x, a.y, a.z, a.w, b.x, b.y, b.z, b.w};
  union { __hip_bfloat16 h[8]; int4 q; } u;
#pragma unroll
  for (int t = 0; t < 8; ++t) {
    float q = rintf(v[t] / s);           // round-half-even, matches np.round
    q = fminf(fmaxf(q, lo), hi);
    u.h[t] = __float2bfloat16(q);        // exact: |q| <= 128
  }
  *(int4*)(out + i) = u.q;
}

// ---------------- GEMM: C[M,N] = A[M,K] * B[N,K]^T, scaled ----------------
// 256 threads = 4 waves; wave tile 64x64 (4x4 of 16x16 MFMA); block tile 128x128.
__global__ __launch_bounds__(256) void gemm_bt(
    const __hip_bfloat16* __restrict__ A,   // [M,K] bf16 (x_q)
    const __hip_bfloat16* __restrict__ B,   // [N,K] bf16 (w_q)
    float* __restrict__ C,                  // [M,N]
    const float* __restrict__ ws_ptr, const float* __restrict__ xs_ptr) {
  __shared__ __attribute__((aligned(16))) char smem[2 * BM * BK * 2];  // sA 8KB + sB 8KB
  char* sA = smem;
  char* sB = smem + BM * BK * 2;

  const int tid  = threadIdx.x;
  const int wave = tid >> 6;
  const int lane = tid & 63;
  const int wr = wave >> 1;       // wave row (0..1) -> 64-row strip
  const int wc = wave & 1;        // wave col (0..1) -> 64-col strip
  const int fr   = lane & 15;     // fragment row/col index
  const int quad = lane >> 4;     // 0..3

  const long m0 = (long)blockIdx.y * BM;
  const long n0 = (long)blockIdx.x * BN;

  // staging: per wave, 2 loads for A + 2 for B per K-tile.
  // load j covers rows (wave*2+j)*16 + (lane>>2), 16B chunk (lane&3) within 64B row.
  const int srow = wave * 32 + (lane >> 2);     // + j*16
  const int scol = (lane & 3) * 8;              // bf16 elements
  const __hip_bfloat16* gA = A + (m0 + srow) * K_DIM + scol;
  const __hip_bfloat16* gB = B + (n0 + srow) * K_DIM + scol;
  // wave-uniform LDS bases (lane writes base + lane*16)
  char* lA0 = sA + wave * 2048;
  char* lA1 = sA + wave * 2048 + 1024;
  char* lB0 = sB + wave * 2048;
  char* lB1 = sB + wave * 2048 + 1024;

  f32x4 acc[4][4] = {};

  for (int k0 = 0; k0 < K_DIM; k0 += BK) {
    __builtin_amdgcn_global_load_lds((gvoid*)(gA),                 (lvoid*)lA0, 16, 0, 0);
    __builtin_amdgcn_global_load_lds((gvoid*)(gA + 16 * K_DIM),    (lvoid*)lA1, 16, 0, 0);
    __builtin_amdgcn_global_load_lds((gvoid*)(gB),                 (lvoid*)lB0, 16, 0, 0);
    __builtin_amdgcn_global_load_lds((gvoid*)(gB + 16 * K_DIM),    (lvoid*)lB1, 16, 0, 0);
    gA += BK;
    gB += BK;
    __syncthreads();   // drains vmcnt (global_load_lds) + workgroup barrier

    bf16x8 a_frag[4], b_frag[4];
#pragma unroll
    for (int i = 0; i < 4; ++i) {
      a_frag[i] = *(const bf16x8*)(sA + (wr * 64 + i * 16 + fr) * (BK * 2) + quad * 16);
      b_frag[i] = *(const bf16x8*)(sB + (wc * 64 + i * 16 + fr) * (BK * 2) + quad * 16);
    }
#pragma unroll
    for (int i = 0; i < 4; ++i)
#pragma unroll
      for (int j = 0; j < 4; ++j)
        acc[i][j] = __builtin_amdgcn_mfma_f32_16x16x32_bf16(a_frag[i], b_frag[j], acc[i][j], 0, 0, 0);

    __syncthreads();   // protect LDS from next iteration's overwrite
  }

  // epilogue: C/D layout col=lane&15, row=quad*4+reg  [verified m89/m91]
  const float s = ws_ptr[0] * xs_ptr[0];
#pragma unroll
  for (int i = 0; i < 4; ++i) {
    const long row0 = m0 + wr * 64 + i * 16 + quad * 4;
#pragma unroll
    for (int j = 0; j < 4; ++j) {
      const long col = n0 + wc * 64 + j * 16 + fr;
#pragma unroll
      for (int r = 0; r < 4; ++r) {
        C[(row0 + r) * N_DIM + col] = acc[i][j][r] * s;
      }
    }
  }
}

extern "C" void kernel_launch(void* const* d_in, const int* in_sizes, int n_in,
                              void* d_out, int out_size, void* d_ws, size_t ws_size,
                              hipStream_t stream) {
  const float* x  = (const float*)d_in[0];   // [8192,4096]
  const float* w  = (const float*)d_in[1];   // [4096,4096]
  const float* ws = (const float*)d_in[2];   // [1]
  const float* xs = (const float*)d_in[3];   // [1]
  float* out = (float*)d_out;

  // workspace layout: x_q bf16 [8192*4096] then w_q bf16 [4096*4096]
  __hip_bfloat16* xq = (__hip_bfloat16*)d_ws;
  __hip_bfloat16* wq = (__hip_bfloat16*)((char*)d_ws + (size_t)M_DIM * K_DIM * 2);

  const long n_x = (long)M_DIM * K_DIM;      // 33.5M
  const long n_w = (long)N_DIM * K_DIM;      // 16.7M

  quant_kernel<<<(n_x / 8 + 255) / 256, 256, 0, stream>>>(x, xq, xs, -128.f, 127.f, n_x);
  quant_kernel<<<(n_w / 8 + 255) / 256, 256, 0, stream>>>(w, wq, ws, -1.f, 1.f, n_w);

  dim3 grid(N_DIM / BN, M_DIM / BM);   // 32 x 64 = 2048 blocks
  gemm_bt<<<grid, 256, 0, stream>>>(xq, wq, out, ws, xs);
}

// Round 2
// 411.867 us; speedup vs baseline: 1.3494x; 1.3494x over previous
//
#include <hip/hip_runtime.h>
#include <hip/hip_bf16.h>
#include <stdint.h>

// BitLinear: out[t,o] = (sum_i clip(rint(x[t,i]/xs),-128,127) * clip(rint(w[o,i]/ws),-1,1)) * xs*ws
// M=8192, N=4096, K=4096.
// R1: int8 end-to-end. x_q fits int8, w_q in {-1,0,1}; i32 accumulation exact
// (|sum| <= 4096*128 = 2^19). mfma_i32_16x16x64_i8 = 2x the bf16 MFMA rate,
// half the staging/fetch bytes of the R0 bf16 path.

typedef int int4v __attribute__((ext_vector_type(4)));

typedef __attribute__((address_space(1))) void gvoid;
typedef __attribute__((address_space(3))) void lvoid;

#define M_DIM 8192
#define N_DIM 4096
#define K_DIM 4096

#define BM 128
#define BN 128
#define BK 64   // K-elements (bytes) per tile iteration

// ---------------- quantize: fp32 -> int8 ----------------
// each thread: 16 elements (four float4 loads, one 16B store)
__global__ __launch_bounds__(256) void quant_kernel(
    const float* __restrict__ in, int8_t* __restrict__ out,
    const float* __restrict__ scale_ptr, float lo, float hi, long n) {
  long i = ((long)blockIdx.x * blockDim.x + threadIdx.x) * 16;
  if (i >= n) return;
  float s = scale_ptr[0];
  float4 a = *(const float4*)(in + i);
  float4 b = *(const float4*)(in + i + 4);
  float4 c = *(const float4*)(in + i + 8);
  float4 d = *(const float4*)(in + i + 12);
  float v[16] = {a.x, a.y, a.z, a.w, b.x, b.y, b.z, b.w,
                 c.x, c.y, c.z, c.w, d.x, d.y, d.z, d.w};
  union { int8_t c[16]; int4 q; } u;
#pragma unroll
  for (int t = 0; t < 16; ++t) {
    float q = rintf(v[t] / s);           // round-half-even, matches np.round
    q = fminf(fmaxf(q, lo), hi);
    u.c[t] = (int8_t)q;
  }
  *(int4*)(out + i) = u.q;
}

// ---------------- GEMM: C[M,N] = A[M,K] * B[N,K]^T (i8 -> i32), scaled ----------------
// 256 threads = 4 waves; wave tile 64x64 (4x4 of 16x16x64 MFMA); block tile 128x128.
__global__ __launch_bounds__(256) void gemm_bt(
    const int8_t* __restrict__ A,   // [M,K] i8 (x_q)
    const int8_t* __restrict__ B,   // [N,K] i8 (w_q)
    float* __restrict__ C,          // [M,N]
    const float* __restrict__ ws_ptr, const float* __restrict__ xs_ptr) {
  __shared__ __attribute__((aligned(16))) char smem[2 * BM * BK];  // sA 8KB + sB 8KB
  char* sA = smem;
  char* sB = smem + BM * BK;

  const int tid  = threadIdx.x;
  const int wave = tid >> 6;
  const int lane = tid & 63;
  const int wr   = wave >> 1;     // wave row (0..1) -> 64-row strip
  const int wc   = wave & 1;      // wave col (0..1) -> 64-col strip
  const int fr   = lane & 15;     // fragment row/col index
  const int quad = lane >> 4;     // 0..3

  const long m0 = (long)blockIdx.y * BM;
  const long n0 = (long)blockIdx.x * BN;

  // staging: per wave, 2 loads for A + 2 for B per K-tile.
  // row = wave*32 + (lane>>2) (+16 for second load), 16B chunk (lane&3) in 64B row.
  const int srow = wave * 32 + (lane >> 2);
  const int scol = (lane & 3) * 16;              // bytes
  const int8_t* gA = A + (m0 + srow) * K_DIM + scol;
  const int8_t* gB = B + (n0 + srow) * K_DIM + scol;
  // wave-uniform LDS bases (lane writes base + lane*16)
  char* lA0 = sA + wave * 2048;
  char* lA1 = sA + wave * 2048 + 1024;
  char* lB0 = sB + wave * 2048;
  char* lB1 = sB + wave * 2048 + 1024;

  int4v acc[4][4] = {};

  for (int k0 = 0; k0 < K_DIM; k0 += BK) {
    __builtin_amdgcn_global_load_lds((gvoid*)(gA),               (lvoid*)lA0, 16, 0, 0);
    __builtin_amdgcn_global_load_lds((gvoid*)(gA + 16 * K_DIM),  (lvoid*)lA1, 16, 0, 0);
    __builtin_amdgcn_global_load_lds((gvoid*)(gB),               (lvoid*)lB0, 16, 0, 0);
    __builtin_amdgcn_global_load_lds((gvoid*)(gB + 16 * K_DIM),  (lvoid*)lB1, 16, 0, 0);
    gA += BK;
    gB += BK;
    __syncthreads();   // drains vmcnt (global_load_lds) + workgroup barrier

    int4v a_frag[4], b_frag[4];
#pragma unroll
    for (int i = 0; i < 4; ++i) {
      // A[m = strip + i*16 + fr][k = quad*16 .. +15]  (16 contiguous i8 = 4 VGPRs)
      a_frag[i] = *(const int4v*)(sA + (wr * 64 + i * 16 + fr) * BK + quad * 16);
      b_frag[i] = *(const int4v*)(sB + (wc * 64 + i * 16 + fr) * BK + quad * 16);
    }
#pragma unroll
    for (int i = 0; i < 4; ++i)
#pragma unroll
      for (int j = 0; j < 4; ++j)
        acc[i][j] = __builtin_amdgcn_mfma_i32_16x16x64_i8(a_frag[i], b_frag[j], acc[i][j], 0, 0, 0);

    __syncthreads();   // protect LDS from next iteration's overwrite
  }

  // epilogue: C/D layout col=lane&15, row=quad*4+reg (shape-determined, dtype-independent)
  const float s = ws_ptr[0] * xs_ptr[0];
#pragma unroll
  for (int i = 0; i < 4; ++i) {
    const long row0 = m0 + wr * 64 + i * 16 + quad * 4;
#pragma unroll
    for (int j = 0; j < 4; ++j) {
      const long col = n0 + wc * 64 + j * 16 + fr;
#pragma unroll
      for (int r = 0; r < 4; ++r) {
        C[(row0 + r) * N_DIM + col] = (float)acc[i][j][r] * s;
      }
    }
  }
}

extern "C" void kernel_launch(void* const* d_in, const int* in_sizes, int n_in,
                              void* d_out, int out_size, void* d_ws, size_t ws_size,
                              hipStream_t stream) {
  const float* x  = (const float*)d_in[0];   // [8192,4096]
  const float* w  = (const float*)d_in[1];   // [4096,4096]
  const float* ws = (const float*)d_in[2];   // [1]
  const float* xs = (const float*)d_in[3];   // [1]
  float* out = (float*)d_out;

  // workspace layout: x_q i8 [8192*4096] then w_q i8 [4096*4096]
  int8_t* xq = (int8_t*)d_ws;
  int8_t* wq = (int8_t*)d_ws + (size_t)M_DIM * K_DIM;

  const long n_x = (long)M_DIM * K_DIM;      // 33.5M
  const long n_w = (long)N_DIM * K_DIM;      // 16.7M

  quant_kernel<<<(n_x / 16 + 255) / 256, 256, 0, stream>>>(x, xq, xs, -128.f, 127.f, n_x);
  quant_kernel<<<(n_w / 16 + 255) / 256, 256, 0, stream>>>(w, wq, ws, -1.f, 1.f, n_w);

  dim3 grid(N_DIM / BN, M_DIM / BM);   // 32 x 64 = 2048 blocks
  gemm_bt<<<grid, 256, 0, stream>>>(xq, wq, out, ws, xs);
}

// Round 3
// 389.832 us; speedup vs baseline: 1.4257x; 1.0565x over previous
//
#include <hip/hip_runtime.h>
#include <hip/hip_bf16.h>
#include <stdint.h>

// BitLinear: out[t,o] = (sum_i clip(rint(x[t,i]/xs),-128,127) * clip(rint(w[o,i]/ws),-1,1)) * xs*ws
// M=8192, N=4096, K=4096.
// R2: i8 GEMM with mfma_i32_32x32x32_i8 (4404 TOPS ceiling vs 3944 for 16x16x64),
// BK=128 (half the barriers, 32KB LDS), and XOR-swizzled LDS layout
// (chunk ^= row&7) so ds_read_b128 fragment loads are bank-conflict-free:
// 128B rows == the 32-bank frame; each 8-lane group tiles the frame exactly.
// Staging keeps global_load_lds's fixed (base + lane*16) LDS dest by permuting
// the *global source* chunk per lane (same 128B segment -> still coalesced).

typedef int  int4v  __attribute__((ext_vector_type(4)));
typedef int  int16v __attribute__((ext_vector_type(16)));

typedef __attribute__((address_space(1))) void gvoid;
typedef __attribute__((address_space(3))) void lvoid;

#define M_DIM 8192
#define N_DIM 4096
#define K_DIM 4096

#define BM 128
#define BN 128
#define BK 128   // K-bytes per tile iteration (one full bank frame per row)

// ---------------- quantize: fp32 -> int8 ----------------
__global__ __launch_bounds__(256) void quant_kernel(
    const float* __restrict__ in, int8_t* __restrict__ out,
    const float* __restrict__ scale_ptr, float lo, float hi, long n) {
  long i = ((long)blockIdx.x * blockDim.x + threadIdx.x) * 16;
  if (i >= n) return;
  float s = scale_ptr[0];
  float4 a = *(const float4*)(in + i);
  float4 b = *(const float4*)(in + i + 4);
  float4 c = *(const float4*)(in + i + 8);
  float4 d = *(const float4*)(in + i + 12);
  float v[16] = {a.x, a.y, a.z, a.w, b.x, b.y, b.z, b.w,
                 c.x, c.y, c.z, c.w, d.x, d.y, d.z, d.w};
  union { int8_t c[16]; int4 q; } u;
#pragma unroll
  for (int t = 0; t < 16; ++t) {
    float q = rintf(v[t] / s);           // round-half-even, matches np.round
    q = fminf(fmaxf(q, lo), hi);
    u.c[t] = (int8_t)q;
  }
  *(int4*)(out + i) = u.q;
}

// ---------------- GEMM: C[M,N] = A[M,K] * B[N,K]^T (i8 -> i32), scaled ----------------
// 256 threads = 4 waves; wave tile 64x64 = 2x2 of 32x32x32 MFMA; block tile 128x128.
__global__ __launch_bounds__(256) void gemm_bt(
    const int8_t* __restrict__ A,   // [M,K] i8 (x_q)
    const int8_t* __restrict__ B,   // [N,K] i8 (w_q)
    float* __restrict__ C,          // [M,N]
    const float* __restrict__ ws_ptr, const float* __restrict__ xs_ptr) {
  __shared__ __attribute__((aligned(16))) char smem[2 * BM * BK];  // sA 16KB + sB 16KB
  char* sA = smem;
  char* sB = smem + BM * BK;

  const int tid  = threadIdx.x;
  const int wave = tid >> 6;
  const int lane = tid & 63;
  const int wr   = wave >> 1;     // wave row (0..1) -> 64-row strip of C
  const int wc   = wave & 1;      // wave col (0..1) -> 64-col strip of C
  const int r    = lane & 31;     // MFMA row/col index within 32-tile
  const int half = lane >> 5;     // 0..1 -> k-half of fragment

  const long m0 = (long)blockIdx.y * BM;
  const long n0 = (long)blockIdx.x * BN;

  // ---- staging addressing ----
  // per global_load_lds: one wave covers 1024B = 8 rows of 128B.
  // lane l -> row (l>>3), LDS chunk (l&7); source chunk = (l&7) ^ (row&7) = (l&7)^(l>>3)
  const int srow   = wave * 32 + (lane >> 3);             // + t*8, t=0..3
  const int schunk = ((lane & 7) ^ (lane >> 3)) * 16;     // swizzled source byte offset
  const int8_t* gA = A + (m0 + srow) * K_DIM + schunk;
  const int8_t* gB = B + (n0 + srow) * K_DIM + schunk;
  char* lA = sA + wave * 4096;   // + t*1024 (HW appends lane*16)
  char* lB = sB + wave * 4096;

  int16v acc[2][2] = {};

  for (int k0 = 0; k0 < K_DIM; k0 += BK) {
#pragma unroll
    for (int t = 0; t < 4; ++t)
      __builtin_amdgcn_global_load_lds((gvoid*)(gA + t * 8 * K_DIM),
                                       (lvoid*)(lA + t * 1024), 16, 0, 0);
#pragma unroll
    for (int t = 0; t < 4; ++t)
      __builtin_amdgcn_global_load_lds((gvoid*)(gB + t * 8 * K_DIM),
                                       (lvoid*)(lB + t * 1024), 16, 0, 0);
    gA += BK;
    gB += BK;
    __syncthreads();   // drains vmcnt (global_load_lds) + workgroup barrier

    // fragment row bases (bytes). row&7 == lane&7 for all lanes.
    const int arow = (wr * 64 + r) * BK;
    const int brow = (wc * 64 + r) * BK;
#pragma unroll
    for (int ks = 0; ks < 4; ++ks) {
      // global k-chunk c = ks*2 + half; LDS chunk = c ^ (row&7)
      const int co = (((ks * 2 + half) ^ (lane & 7)) * 16);
      int4v a0 = *(const int4v*)(sA + arow + co);
      int4v a1 = *(const int4v*)(sA + arow + 32 * BK + co);
      int4v b0 = *(const int4v*)(sB + brow + co);
      int4v b1 = *(const int4v*)(sB + brow + 32 * BK + co);
      acc[0][0] = __builtin_amdgcn_mfma_i32_32x32x32_i8(a0, b0, acc[0][0], 0, 0, 0);
      acc[0][1] = __builtin_amdgcn_mfma_i32_32x32x32_i8(a0, b1, acc[0][1], 0, 0, 0);
      acc[1][0] = __builtin_amdgcn_mfma_i32_32x32x32_i8(a1, b0, acc[1][0], 0, 0, 0);
      acc[1][1] = __builtin_amdgcn_mfma_i32_32x32x32_i8(a1, b1, acc[1][1], 0, 0, 0);
    }

    __syncthreads();   // protect LDS from next iteration's overwrite
  }

  // epilogue: 32x32 C/D layout col=lane&31, row=(reg&3)+8*(reg>>2)+4*(lane>>5)
  // [verified m74/m101; dtype-independent m121-m128]
  const float s = ws_ptr[0] * xs_ptr[0];
#pragma unroll
  for (int mb = 0; mb < 2; ++mb) {
#pragma unroll
    for (int nb = 0; nb < 2; ++nb) {
      const long col = n0 + wc * 64 + nb * 32 + r;
      const long rowbase = m0 + wr * 64 + mb * 32 + 4 * half;
#pragma unroll
      for (int reg = 0; reg < 16; ++reg) {
        const long row = rowbase + (reg & 3) + 8 * (reg >> 2);
        C[row * N_DIM + col] = (float)acc[mb][nb][reg] * s;
      }
    }
  }
}

extern "C" void kernel_launch(void* const* d_in, const int* in_sizes, int n_in,
                              void* d_out, int out_size, void* d_ws, size_t ws_size,
                              hipStream_t stream) {
  const float* x  = (const float*)d_in[0];   // [8192,4096]
  const float* w  = (const float*)d_in[1];   // [4096,4096]
  const float* ws = (const float*)d_in[2];   // [1]
  const float* xs = (const float*)d_in[3];   // [1]
  float* out = (float*)d_out;

  int8_t* xq = (int8_t*)d_ws;
  int8_t* wq = (int8_t*)d_ws + (size_t)M_DIM * K_DIM;

  const long n_x = (long)M_DIM * K_DIM;
  const long n_w = (long)N_DIM * K_DIM;

  quant_kernel<<<(n_x / 16 + 255) / 256, 256, 0, stream>>>(x, xq, xs, -128.f, 127.f, n_x);
  quant_kernel<<<(n_w / 16 + 255) / 256, 256, 0, stream>>>(w, wq, ws, -1.f, 1.f, n_w);

  dim3 grid(N_DIM / BN, M_DIM / BM);   // 32 x 64 = 2048 blocks
  gemm_bt<<<grid, 256, 0, stream>>>(xq, wq, out, ws, xs);
}